// Round 4
// baseline (380.678 us; speedup 1.0000x reference)
//
#include <hip/hip_runtime.h>
#include <float.h>

// LocalAttention: B=4, N=4096, DIM=1024, WINDOW=128. v2=k2 reference bug
// exploited (V projection dead). bf16 MFMA 16x16x32, fp32 acc everywhere.
// R4: qk-proj and out-proj moved to 256x256 8-phase template (T1+T2+T3+T4+T5).

#define B_SZ 4
#define SEQ 4096
#define DIM 1024
#define WIN 128
#define NWIN 32
#define TW 256
#define NROWS (B_SZ * SEQ)     // 16384
#define KPAD 4224              // 128 zero rows + 4096 tokens per batch

typedef float f32x4 __attribute__((ext_vector_type(4)));
typedef __bf16 bf16x8 __attribute__((ext_vector_type(8)));

__device__ __forceinline__ unsigned short f2b(float f) {
    unsigned int u = __float_as_uint(f);
    u += 0x7FFF + ((u >> 16) & 1);          // round-to-nearest-even
    return (unsigned short)(u >> 16);
}

__device__ __forceinline__ void gld_lds16(const unsigned short* g, unsigned short* l) {
    __builtin_amdgcn_global_load_lds(
        (const __attribute__((address_space(1))) void*)g,
        (__attribute__((address_space(3))) void*)l, 16, 0, 0);
}

// ===========================================================================
// 256x256 8-phase GEMM core (m201 template, plain HIP).
// C(256x256) = A(256xK) * Bt(256xK)^T. 512 thr = 8 waves (2M x 4N).
// Per wave: 128x64 out = acc[8][4] f32x4. BK=64, dbuf LDS 128KB.
// st_16x32 swizzle: byte ^= ((byte>>9)&1)<<5 within each 32KB tile buffer;
// applied via pre-swizzled GLOBAL source (linear gld_lds dest) + swizzled
// ds_read address (both sides, same involution).
// Race safety: quadrants (0,0),(1,0),(1,1),(0,1); A-reads lgkm-complete by
// barrier2(P1) -> A-halves of tile t+2 staged in P2; B by P2 -> staged in P3.
// vmcnt(8) once per K-tile = 1 full tile (8 loads/wave) stays in flight.
// ===========================================================================
__device__ __forceinline__ bf16x8 lds_read_swz(const unsigned short* tb, int row, int kbyte) {
    int L = row * 128 + kbyte;
    L ^= ((L >> 9) & 1) << 5;
    return *(const bf16x8*)((const char*)tb + L);
}

#define BAR __builtin_amdgcn_s_barrier()
#define PRI1 __builtin_amdgcn_s_setprio(1)
#define PRI0 __builtin_amdgcn_s_setprio(0)
#define WAIT_LGKM0 do { asm volatile("s_waitcnt lgkmcnt(0)" ::: "memory"); \
                        __builtin_amdgcn_sched_barrier(0); } while (0)
#define WAIT_VM8   do { asm volatile("s_waitcnt vmcnt(8)" ::: "memory");  \
                        __builtin_amdgcn_sched_barrier(0); } while (0)
#define WAIT_VM0   do { asm volatile("s_waitcnt vmcnt(0)" ::: "memory");  \
                        __builtin_amdgcn_sched_barrier(0); } while (0)

#define LDAF(BUF, MH)                                                        \
    _Pragma("unroll") for (int m_ = 0; m_ < 4; ++m_)                         \
    _Pragma("unroll") for (int ks_ = 0; ks_ < 2; ++ks_)                      \
        afq[MH][m_][ks_] = lds_read_swz(bufA[BUF],                           \
            wr * 128 + (MH) * 64 + m_ * 16 + fr, ks_ * 64 + kby);

#define LDBF(BUF, NH)                                                        \
    _Pragma("unroll") for (int n_ = 0; n_ < 2; ++n_)                         \
    _Pragma("unroll") for (int ks_ = 0; ks_ < 2; ++ks_)                      \
        bfq[n_][ks_] = lds_read_swz(bufB[BUF],                               \
            wc * 64 + (NH) * 32 + n_ * 16 + fr, ks_ * 64 + kby);

#define MFQ(MH, NH)                                                          \
    _Pragma("unroll") for (int ks_ = 0; ks_ < 2; ++ks_)                      \
    _Pragma("unroll") for (int m_ = 0; m_ < 4; ++m_)                         \
    _Pragma("unroll") for (int n_ = 0; n_ < 2; ++n_)                         \
        acc[(MH) * 4 + m_][(NH) * 2 + n_] =                                  \
            __builtin_amdgcn_mfma_f32_16x16x32_bf16(afq[MH][m_][ks_],        \
                bfq[n_][ks_], acc[(MH) * 4 + m_][(NH) * 2 + n_], 0, 0, 0);

#define STG_A(BUF, HJ, K0) gld_lds16(A + soffA[HJ] + (K0), bufA[BUF] + ldst[HJ])
#define STG_B(BUF, HJ, K0) gld_lds16(Bt + soffB[HJ] + (K0), bufB[BUF] + ldst[HJ])

// phases 0-3 for one K-tile in buffer BUF; stages tile(+2) halves at KST.
#define PHASES03(BUF, KST, ST)                                               \
    LDAF(BUF, 0); LDBF(BUF, 0);                                              \
    BAR; WAIT_LGKM0; PRI1; MFQ(0, 0); PRI0; BAR;                             \
    LDAF(BUF, 1);                                                            \
    BAR; WAIT_LGKM0; PRI1; MFQ(1, 0); PRI0; BAR;                             \
    LDBF(BUF, 1);                                                            \
    if (ST) { STG_A(BUF, 0, KST); STG_A(BUF, 1, KST);                        \
              STG_A(BUF, 2, KST); STG_A(BUF, 3, KST); }                      \
    BAR; WAIT_LGKM0; PRI1; MFQ(1, 1); PRI0; BAR;                             \
    if (ST) { STG_B(BUF, 0, KST); STG_B(BUF, 1, KST);                        \
              STG_B(BUF, 2, KST); STG_B(BUF, 3, KST); }                      \
    BAR; WAIT_LGKM0; PRI1; MFQ(0, 1); PRI0;

__device__ __forceinline__ void core256(
    const unsigned short* __restrict__ A, int lda,
    const unsigned short* __restrict__ Bt, int ldb, int K,
    unsigned short* lds, f32x4 (&acc)[8][4],
    int wid, int lane, int wr, int wc)
{
    unsigned short* bufA[2] = { lds, lds + 32768 };
    unsigned short* bufB[2] = { lds + 16384, lds + 49152 };

    const int kby = (lane >> 4) * 16;
    const int fr = lane & 15;

    // per-lane pre-swizzled stage source offsets (elements); LDS dest linear.
    int soffA[4], soffB[4], ldst[4];
#pragma unroll
    for (int hj = 0; hj < 4; ++hj) {
        const int half = hj >> 1, j = hj & 1;
        const int P = half * 16384 + wid * 2048 + j * 1024 + lane * 16; // bytes in tile
        const int L = P ^ (((P >> 9) & 1) << 5);
        const int row = L >> 7, col = (L & 127) >> 1;
        soffA[hj] = row * lda + col;
        soffB[hj] = row * ldb + col;
        ldst[hj] = (half * 16384 + wid * 2048 + j * 1024) >> 1;  // ushorts, uniform
    }

    bf16x8 afq[2][4][2], bfq[2][2];
#pragma unroll
    for (int m = 0; m < 8; ++m)
#pragma unroll
        for (int n = 0; n < 4; ++n) acc[m][n] = (f32x4){0.f, 0.f, 0.f, 0.f};

    // prologue: stage tiles 0 (buf0) and 1 (buf1); keep tile1 in flight.
#pragma unroll
    for (int hj = 0; hj < 4; ++hj) STG_A(0, hj, 0);
#pragma unroll
    for (int hj = 0; hj < 4; ++hj) STG_B(0, hj, 0);
#pragma unroll
    for (int hj = 0; hj < 4; ++hj) STG_A(1, hj, 64);
#pragma unroll
    for (int hj = 0; hj < 4; ++hj) STG_B(1, hj, 64);
    WAIT_VM8;
    BAR;

    const int NITER = K >> 7;   // 2 K-tiles (BK=64) per iteration
#pragma unroll 1
    for (int i = 0; i < NITER; ++i) {
        const bool st = (i + 1 < NITER);
        const int ka = (2 * i + 2) * 64;
        const int kb = (2 * i + 3) * 64;
        // ---- tile 2i from buf0; stage tile 2i+2 -> buf0 ----
        PHASES03(0, ka, st)
        if (st) { WAIT_VM8; } else { WAIT_VM0; }
        BAR;
        // ---- tile 2i+1 from buf1; stage tile 2i+3 -> buf1 ----
        PHASES03(1, kb, st)
        if (st) { WAIT_VM8; }
        BAR;
    }
}

// ---------------------------------------------------------------------------
// 128x128 4-wave core (m97 structure) — kept for the small window GEMMs.
// ---------------------------------------------------------------------------
__device__ __forceinline__ void mfma_core(
    const unsigned short* __restrict__ A, int lda,
    const unsigned short* __restrict__ Bt, int ldb, int K,
    unsigned short* As, unsigned short* Bs, f32x4 (&acc)[4][4])
{
    const int tid = threadIdx.x;
    const int wv = tid >> 6, lane = tid & 63;
    const int wr = wv >> 1, wc = wv & 1;

#pragma unroll
    for (int m = 0; m < 4; ++m)
#pragma unroll
        for (int n = 0; n < 4; ++n) acc[m][n] = (f32x4){0.f, 0.f, 0.f, 0.f};

    for (int k0 = 0; k0 < K; k0 += 64) {
#pragma unroll
        for (int it = 0; it < 4; ++it) {
            int rbase = wv * 32 + it * 8;
            const unsigned short* g =
                A + (size_t)(rbase + (lane >> 3)) * lda + k0 + (lane & 7) * 8;
            gld_lds16(g, As + rbase * 64);
        }
#pragma unroll
        for (int it = 0; it < 4; ++it) {
            int rbase = wv * 32 + it * 8;
            const unsigned short* g =
                Bt + (size_t)(rbase + (lane >> 3)) * ldb + k0 + (lane & 7) * 8;
            gld_lds16(g, Bs + rbase * 64);
        }
        __syncthreads();

#pragma unroll
        for (int ks = 0; ks < 2; ++ks) {
            bf16x8 af[4], bfr[4];
            const int kof = ks * 32 + (lane >> 4) * 8;
#pragma unroll
            for (int m = 0; m < 4; ++m)
                af[m] = *(const bf16x8*)(As + (wr * 64 + m * 16 + (lane & 15)) * 64 + kof);
#pragma unroll
            for (int n = 0; n < 4; ++n)
                bfr[n] = *(const bf16x8*)(Bs + (wc * 64 + n * 16 + (lane & 15)) * 64 + kof);
#pragma unroll
            for (int m = 0; m < 4; ++m)
#pragma unroll
                for (int n = 0; n < 4; ++n)
                    acc[m][n] = __builtin_amdgcn_mfma_f32_16x16x32_bf16(
                        af[m], bfr[n], acc[m][n], 0, 0, 0);
        }
        __syncthreads();
    }
}

// ---------------------------------------------------------------------------
// Prepass kernels
// ---------------------------------------------------------------------------
__global__ __launch_bounds__(256) void k_prep_x(const float* __restrict__ x,
                                                unsigned short* __restrict__ xb)
{
    int i = blockIdx.x * 256 + threadIdx.x;
    float4 a = *(const float4*)&x[(size_t)i * 8];
    float4 b = *(const float4*)&x[(size_t)i * 8 + 4];
    ushort4 lo, hi;
    lo.x = f2b(a.x); lo.y = f2b(a.y); lo.z = f2b(a.z); lo.w = f2b(a.w);
    hi.x = f2b(b.x); hi.y = f2b(b.y); hi.z = f2b(b.z); hi.w = f2b(b.w);
    *(ushort4*)&xb[(size_t)i * 8] = lo;
    *(ushort4*)&xb[(size_t)i * 8 + 4] = hi;
}

__global__ __launch_bounds__(256) void k_transpose(const float* __restrict__ src,
    int src_ld, int col0, int R, unsigned short* __restrict__ dst)
{
    __shared__ float T[32][33];
    const int r0 = blockIdx.y * 32, c0 = blockIdx.x * 32;
    const int cx = threadIdx.x & 31, ry = threadIdx.x >> 5;
#pragma unroll
    for (int i = 0; i < 4; ++i)
        T[ry + 8 * i][cx] = src[(size_t)(r0 + ry + 8 * i) * src_ld + col0 + c0 + cx];
    __syncthreads();
#pragma unroll
    for (int i = 0; i < 4; ++i)
        dst[(size_t)(c0 + ry + 8 * i) * R + r0 + cx] = f2b(T[cx][ry + 8 * i]);
}

__global__ __launch_bounds__(256) void k_zero_kpad(unsigned short* __restrict__ kbuf)
{
    int t = blockIdx.x * 256 + threadIdx.x;
    int b = t >> 14, r = t & 16383;
    float4 z = {0.f, 0.f, 0.f, 0.f};
    *(float4*)&kbuf[(size_t)b * KPAD * DIM + (size_t)r * 8] = z;
}

__global__ __launch_bounds__(256) void k_zero_ktpad(unsigned short* __restrict__ ktr)
{
    int t = blockIdx.x * 256 + threadIdx.x;
    int b = t >> 14, rem = t & 16383;
    int d = rem >> 4, s = rem & 15;
    float4 z = {0.f, 0.f, 0.f, 0.f};
    *(float4*)&ktr[((size_t)b * DIM + d) * KPAD + s * 8] = z;
}

// ---------------------------------------------------------------------------
// qk-proj (256^2 8-phase): xb(16384x1024) x wqkvT(2048x1024)^T.
// grid 512 blocks x 512 thr; XCD swizzle chunk=64 (512%8==0).
// ---------------------------------------------------------------------------
__global__ __launch_bounds__(512, 2) void k_gemm_qk(
    const unsigned short* __restrict__ xb, const unsigned short* __restrict__ wqkvT,
    unsigned short* __restrict__ qbuf, unsigned short* __restrict__ kbuf,
    unsigned short* __restrict__ ktr)
{
    __shared__ unsigned short lds[65536];   // 128 KB
    const int tid = threadIdx.x, wid = tid >> 6, lane = tid & 63;
    const int wr = wid >> 2, wc = wid & 3;
    const int wg = blockIdx.x;
    const int x = (wg & 7) * 64 + (wg >> 3);
    const int bm = (x & 63) * 256;
    const int bn = (x >> 6) * 256;          // consecutive-in-XCD share B panel

    f32x4 acc[8][4];
    core256(xb + (size_t)bm * DIM, DIM, wqkvT + (size_t)bn * DIM, DIM, DIM,
            lds, acc, wid, lane, wr, wc);

    const int fr = lane & 15;
#pragma unroll
    for (int m = 0; m < 8; ++m) {
        const int row0 = bm + wr * 128 + m * 16 + (lane >> 4) * 4;
#pragma unroll
        for (int n = 0; n < 4; ++n) {
            const int col = bn + wc * 64 + n * 16 + fr;
            if (col < DIM) {
#pragma unroll
                for (int r = 0; r < 4; ++r)
                    qbuf[(size_t)(row0 + r) * DIM + col] = f2b(acc[m][n][r]);
            } else {
                const int d = col - DIM;
                const int b = row0 >> 12, tok0 = row0 & 4095;
#pragma unroll
                for (int r = 0; r < 4; ++r)
                    kbuf[((size_t)b * KPAD + 128 + tok0 + r) * DIM + d] = f2b(acc[m][n][r]);
                ushort4 kt;
                kt.x = f2b(acc[m][n][0]); kt.y = f2b(acc[m][n][1]);
                kt.z = f2b(acc[m][n][2]); kt.w = f2b(acc[m][n][3]);
                *(ushort4*)&ktr[((size_t)b * DIM + d) * KPAD + 128 + tok0] = kt;
            }
        }
    }
}

// ---------------------------------------------------------------------------
// out-proj (256^2 8-phase): aout(16384x1024) x woutT(1024x1024)^T + bias.
// grid 256 blocks; XCD swizzle chunk=32.
// ---------------------------------------------------------------------------
__global__ __launch_bounds__(512, 2) void k_out(
    const unsigned short* __restrict__ aout, const unsigned short* __restrict__ woutT,
    const float* __restrict__ bias, float* __restrict__ out)
{
    __shared__ unsigned short lds[65536];
    const int tid = threadIdx.x, wid = tid >> 6, lane = tid & 63;
    const int wr = wid >> 2, wc = wid & 3;
    const int wg = blockIdx.x;
    const int x = (wg & 7) * 32 + (wg >> 3);
    const int bm = (x & 63) * 256;
    const int bn = (x >> 6) * 256;

    f32x4 acc[8][4];
    core256(aout + (size_t)bm * DIM, DIM, woutT + (size_t)bn * DIM, DIM, DIM,
            lds, acc, wid, lane, wr, wc);

    const int fr = lane & 15;
#pragma unroll
    for (int m = 0; m < 8; ++m) {
        const int row0 = bm + wr * 128 + m * 16 + (lane >> 4) * 4;
#pragma unroll
        for (int n = 0; n < 4; ++n) {
            const int col = bn + wc * 64 + n * 16 + fr;
            const float bb = bias[col];
#pragma unroll
            for (int r = 0; r < 4; ++r)
                out[(size_t)(row0 + r) * DIM + col] = acc[m][n][r] + bb;
        }
    }
}

// ---------------------------------------------------------------------------
// sim = q.k2^T * scale, masked -> fp32. grid (2, 128). (unchanged)
// ---------------------------------------------------------------------------
__global__ __launch_bounds__(256) void k_sim(
    const unsigned short* __restrict__ qbuf, const unsigned short* __restrict__ kbuf,
    float* __restrict__ sim)
{
    __shared__ unsigned short As[128 * 64], Bs[128 * 64];
    f32x4 acc[4][4];
    const int win = blockIdx.y, ct = blockIdx.x;
    const int b = win >> 5, w = win & 31;
    const unsigned short* Ap = qbuf + ((size_t)b * SEQ + w * WIN) * DIM;
    const unsigned short* Bp = kbuf + ((size_t)b * KPAD + w * WIN + ct * 128) * DIM;
    mfma_core(Ap, DIM, Bp, DIM, DIM, As, Bs, acc);

    const int tid = threadIdx.x, wv = tid >> 6, lane = tid & 63;
    const int wr = wv >> 1, wc = wv & 1;
    const float scale = 0.03125f;
#pragma unroll
    for (int m = 0; m < 4; ++m) {
        const int qi0 = wr * 64 + m * 16 + (lane >> 4) * 4;
#pragma unroll
        for (int n = 0; n < 4; ++n) {
            const int jc = ct * 128 + wc * 64 + n * 16 + (lane & 15);
#pragma unroll
            for (int r = 0; r < 4; ++r) {
                const int qi = qi0 + r;
                float v = (jc > qi + WIN) ? -FLT_MAX : acc[m][n][r] * scale;
                sim[((size_t)win * WIN + qi) * TW + jc] = v;
            }
        }
    }
}

__global__ __launch_bounds__(256) void k_softmax(const float* __restrict__ sim,
                                                 unsigned short* __restrict__ attnb)
{
    const int row = blockIdx.x * 4 + (threadIdx.x >> 6);
    const int lane = threadIdx.x & 63;
    const float* p = sim + (size_t)row * TW;
    float4 v = *(const float4*)&p[lane * 4];
    float m = fmaxf(fmaxf(v.x, v.y), fmaxf(v.z, v.w));
#pragma unroll
    for (int off = 32; off; off >>= 1) m = fmaxf(m, __shfl_xor(m, off));
    float e0 = expf(v.x - m), e1 = expf(v.y - m);
    float e2 = expf(v.z - m), e3 = expf(v.w - m);
    float s = e0 + e1 + e2 + e3;
#pragma unroll
    for (int off = 32; off; off >>= 1) s += __shfl_xor(s, off);
    float inv = 1.f / s;
    ushort4 o;
    o.x = f2b(e0 * inv); o.y = f2b(e1 * inv); o.z = f2b(e2 * inv); o.w = f2b(e3 * inv);
    *(ushort4*)&attnb[(size_t)row * TW + lane * 4] = o;
}

__global__ __launch_bounds__(256) void k_pv(
    const unsigned short* __restrict__ attnb, const unsigned short* __restrict__ ktr,
    unsigned short* __restrict__ aout)
{
    __shared__ unsigned short As[128 * 64], Bs[128 * 64];
    f32x4 acc[4][4];
    const int win = blockIdx.y, ct = blockIdx.x;
    const int b = win >> 5, w = win & 31;
    const unsigned short* Ap = attnb + (size_t)win * WIN * TW;
    const unsigned short* Bp = ktr + ((size_t)b * DIM + ct * 128) * KPAD + w * WIN;
    mfma_core(Ap, TW, Bp, KPAD, TW, As, Bs, acc);

    const int tid = threadIdx.x, wv = tid >> 6, lane = tid & 63;
    const int wr = wv >> 1, wc = wv & 1;
#pragma unroll
    for (int m = 0; m < 4; ++m) {
        const int row0 = wr * 64 + m * 16 + (lane >> 4) * 4;
#pragma unroll
        for (int n = 0; n < 4; ++n) {
            const int col = ct * 128 + wc * 64 + n * 16 + (lane & 15);
#pragma unroll
            for (int r = 0; r < 4; ++r)
                aout[((size_t)b * SEQ + w * WIN + row0 + r) * DIM + col] =
                    f2b(acc[m][n][r]);
        }
    }
}

// ---------------------------------------------------------------------------
extern "C" void kernel_launch(void* const* d_in, const int* in_sizes, int n_in,
                              void* d_out, int out_size, void* d_ws, size_t ws_size,
                              hipStream_t stream)
{
    const float* x     = (const float*)d_in[0];
    const float* w_qkv = (const float*)d_in[1];
    const float* w_out = (const float*)d_in[2];
    const float* b_out = (const float*)d_in[3];
    float* out = (float*)d_out;

    char* p = (char*)d_ws;
    unsigned short* xb    = (unsigned short*)p; p += (size_t)NROWS * DIM * 2;
    unsigned short* wqkvT = (unsigned short*)p; p += (size_t)2 * DIM * DIM * 2;
    unsigned short* woutT = (unsigned short*)p; p += (size_t)DIM * DIM * 2;
    unsigned short* qbuf  = (unsigned short*)p; p += (size_t)NROWS * DIM * 2;
    unsigned short* kbuf  = (unsigned short*)p; p += (size_t)B_SZ * KPAD * DIM * 2;
    unsigned short* ktr   = (unsigned short*)p; p += (size_t)B_SZ * DIM * KPAD * 2;
    float*          simb  = (float*)p;          p += (size_t)NROWS * TW * 4;
    unsigned short* attnb = (unsigned short*)p; p += (size_t)NROWS * TW * 2;
    unsigned short* aout  = (unsigned short*)p; p += (size_t)NROWS * DIM * 2;

    k_prep_x<<<NROWS * DIM / 8 / 256, 256, 0, stream>>>(x, xb);
    k_transpose<<<dim3(2 * DIM / 32, DIM / 32), 256, 0, stream>>>(w_qkv, 3 * DIM, 0, DIM, wqkvT);
    k_transpose<<<dim3(DIM / 32, DIM / 32), 256, 0, stream>>>(w_out, DIM, 0, DIM, woutT);
    k_zero_kpad<<<256, 256, 0, stream>>>(kbuf);
    k_zero_ktpad<<<256, 256, 0, stream>>>(ktr);

    k_gemm_qk<<<512, 512, 0, stream>>>(xb, wqkvT, qbuf, kbuf, ktr);
    k_sim<<<dim3(2, B_SZ * NWIN), 256, 0, stream>>>(qbuf, kbuf, simb);
    k_softmax<<<NROWS / 4, 256, 0, stream>>>(simb, attnb);
    k_pv<<<dim3(DIM / 128, B_SZ * NWIN), 256, 0, stream>>>(attnb, ktr, aout);
    k_out<<<256, 512, 0, stream>>>(aout, woutT, b_out, out);
}

// Round 6
// 366.134 us; speedup vs baseline: 1.0397x; 1.0397x over previous
//
#include <hip/hip_runtime.h>
#include <float.h>

// LocalAttention: B=4, N=4096, DIM=1024, WINDOW=128. v2=k2 reference bug
// exploited (V projection dead). bf16 MFMA 16x16x32, fp32 acc everywhere.
// R5: faithful m201 8-phase schedule (per-phase half-tile staging, counted
// vmcnt(4)/vmcnt(6), never drain in main loop) for qk-proj and out-proj.

#define B_SZ 4
#define SEQ 4096
#define DIM 1024
#define WIN 128
#define NWIN 32
#define TW 256
#define NROWS (B_SZ * SEQ)     // 16384
#define KPAD 4224              // 128 zero rows + 4096 tokens per batch

typedef float f32x4 __attribute__((ext_vector_type(4)));
typedef __bf16 bf16x8 __attribute__((ext_vector_type(8)));

__device__ __forceinline__ unsigned short f2b(float f) {
    unsigned int u = __float_as_uint(f);
    u += 0x7FFF + ((u >> 16) & 1);          // round-to-nearest-even
    return (unsigned short)(u >> 16);
}

__device__ __forceinline__ void gld_lds16(const unsigned short* g, unsigned short* l) {
    __builtin_amdgcn_global_load_lds(
        (const __attribute__((address_space(1))) void*)g,
        (__attribute__((address_space(3))) void*)l, 16, 0, 0);
}

// ===========================================================================
// 256x256 8-phase GEMM core, m201-faithful schedule.
// C(256x256) = A(256xK) * Bt(256xK)^T. 512 thr = 8 waves (2M x 4N).
// Per wave: 128x64 out = acc[8][4] f32x4. BK=64, dbuf LDS 128KB.
// st_16x32 swizzle via pre-swizzled global source + swizzled ds_read.
// Stage plan (one half-tile ~= 2 loads/thread per phase):
//   P0: B-HI(buf1,u+1)   P2: A-LO(buf0,u+2)  P3: A-HI(buf0,u+2)
//   P4: B-LO(buf0,u+2)   P5: B-HI(buf0,u+2)  P6: A-LO(buf1,u+3)
//   P7: A-HI(buf1,u+3)+B-LO(buf1,u+3)        next-P0: B-HI(buf1,u+3)
// vmcnt(4) end of P3 (buf1 tile fully landed; 2 HT in flight),
// vmcnt(6) end of P7 (buf0 next tile landed; 3 HT in flight).
// Region-free proofs: A-halves read only in P0/P1 (P4/P5 for buf1), free
// after that phase's lgkm0+barrier; B-halves read in P0/P2 (P4/P6), free
// after P2 (P6). All stage slots are later than the freeing barrier.
// ===========================================================================
__device__ __forceinline__ bf16x8 lds_read_swz(const unsigned short* tb, int row, int kbyte) {
    int L = row * 128 + kbyte;
    L ^= ((L >> 9) & 1) << 5;
    return *(const bf16x8*)((const char*)tb + L);
}

#define BAR __builtin_amdgcn_s_barrier()
#define PRI1 __builtin_amdgcn_s_setprio(1)
#define PRI0 __builtin_amdgcn_s_setprio(0)
#define LGKM0 do { asm volatile("s_waitcnt lgkmcnt(0)" ::: "memory"); \
                   __builtin_amdgcn_sched_barrier(0); } while (0)
#define VMW(N) do { asm volatile("s_waitcnt vmcnt(" #N ")" ::: "memory"); \
                    __builtin_amdgcn_sched_barrier(0); } while (0)

#define LDAF(BUF, MH)                                                        \
    _Pragma("unroll") for (int m_ = 0; m_ < 4; ++m_)                         \
    _Pragma("unroll") for (int ks_ = 0; ks_ < 2; ++ks_)                      \
        afq[MH][m_][ks_] = lds_read_swz(bufA[BUF],                           \
            wr * 128 + (MH) * 64 + m_ * 16 + fr, ks_ * 64 + kby);

#define LDBF(BUF, NH)                                                        \
    _Pragma("unroll") for (int n_ = 0; n_ < 2; ++n_)                         \
    _Pragma("unroll") for (int ks_ = 0; ks_ < 2; ++ks_)                      \
        bfq[n_][ks_] = lds_read_swz(bufB[BUF],                               \
            wc * 64 + (NH) * 32 + n_ * 16 + fr, ks_ * 64 + kby);

#define MFQ(MH, NH)                                                          \
    _Pragma("unroll") for (int ks_ = 0; ks_ < 2; ++ks_)                      \
    _Pragma("unroll") for (int m_ = 0; m_ < 4; ++m_)                         \
    _Pragma("unroll") for (int n_ = 0; n_ < 2; ++n_)                         \
        acc[(MH) * 4 + m_][(NH) * 2 + n_] =                                  \
            __builtin_amdgcn_mfma_f32_16x16x32_bf16(afq[MH][m_][ks_],        \
                bfq[n_][ks_], acc[(MH) * 4 + m_][(NH) * 2 + n_], 0, 0, 0);

// stage one half-tile (2 loads/thread). HALF: 0 = rows 0-127, 1 = rows 128-255
#define STG_HA(BUF, HALF, K0)                                                \
    { gld_lds16(A + soffA[(HALF) * 2 + 0] + (K0), bufA[BUF] + ldst[(HALF) * 2 + 0]); \
      gld_lds16(A + soffA[(HALF) * 2 + 1] + (K0), bufA[BUF] + ldst[(HALF) * 2 + 1]); }
#define STG_HB(BUF, HALF, K0)                                                \
    { gld_lds16(Bt + soffB[(HALF) * 2 + 0] + (K0), bufB[BUF] + ldst[(HALF) * 2 + 0]); \
      gld_lds16(Bt + soffB[(HALF) * 2 + 1] + (K0), bufB[BUF] + ldst[(HALF) * 2 + 1]); }

__device__ __forceinline__ void core256(
    const unsigned short* __restrict__ A, int lda,
    const unsigned short* __restrict__ Bt, int ldb, int K,
    unsigned short* lds, f32x4 (&acc)[8][4],
    int wid, int lane, int wr, int wc)
{
    unsigned short* bufA[2] = { lds, lds + 32768 };
    unsigned short* bufB[2] = { lds + 16384, lds + 49152 };

    const int kby = (lane >> 4) * 16;
    const int fr = lane & 15;

    // per-lane pre-swizzled stage source offsets (elements); LDS dest linear.
    int soffA[4], soffB[4], ldst[4];
#pragma unroll
    for (int hj = 0; hj < 4; ++hj) {
        const int half = hj >> 1, j = hj & 1;
        const int P = half * 16384 + wid * 2048 + j * 1024 + lane * 16; // bytes
        const int L = P ^ (((P >> 9) & 1) << 5);
        const int row = L >> 7, col = (L & 127) >> 1;
        soffA[hj] = row * lda + col;
        soffB[hj] = row * ldb + col;
        ldst[hj] = (half * 16384 + wid * 2048 + j * 1024) >> 1;  // ushorts
    }

    bf16x8 afq[2][4][2], bfq[2][2];
#pragma unroll
    for (int m = 0; m < 8; ++m)
#pragma unroll
        for (int n = 0; n < 4; ++n) acc[m][n] = (f32x4){0.f, 0.f, 0.f, 0.f};

    // Prologue: tile0 fully -> buf0 (4 HT), tile1 A-LO/A-HI/B-LO -> buf1 (3 HT).
    STG_HA(0, 0, 0); STG_HA(0, 1, 0); STG_HB(0, 0, 0); STG_HB(0, 1, 0);
    STG_HA(1, 0, 64); STG_HA(1, 1, 64); STG_HB(1, 0, 64);
    VMW(6);            // tile0 landed; 3 HT (tile1) in flight
    BAR;

    const int NITER = K >> 7;   // 2 K-tiles (BK=64) per iteration
#pragma unroll 1
    for (int i = 0; i < NITER; ++i) {
        const bool st = (i + 1 < NITER);
        const int ku1 = (2 * i + 1) * 64;
        const int ku2 = (2 * i + 2) * 64;
        const int ku3 = (2 * i + 3) * 64;

        // P0: quadrant (0,0) of buf0; stage B-HI(buf1, u+1)
        LDAF(0, 0); LDBF(0, 0);
        STG_HB(1, 1, ku1);
        BAR; LGKM0; PRI1; MFQ(0, 0); PRI0; BAR;
        // P1: quadrant (1,0)
        LDAF(0, 1);
        BAR; LGKM0; PRI1; MFQ(1, 0); PRI0; BAR;
        // P2: quadrant (1,1); stage A-LO(buf0, u+2)
        LDBF(0, 1);
        if (st) STG_HA(0, 0, ku2);
        BAR; LGKM0; PRI1; MFQ(1, 1); PRI0; BAR;
        // P3: quadrant (0,1); stage A-HI(buf0, u+2); counted wait for buf1
        if (st) { STG_HA(0, 1, ku2); VMW(4); } else { VMW(0); }
        BAR; PRI1; MFQ(0, 1); PRI0; BAR;
        // P4: quadrant (0,0) of buf1; stage B-LO(buf0, u+2)
        LDAF(1, 0); LDBF(1, 0);
        if (st) STG_HB(0, 0, ku2);
        BAR; LGKM0; PRI1; MFQ(0, 0); PRI0; BAR;
        // P5: quadrant (1,0); stage B-HI(buf0, u+2)
        LDAF(1, 1);
        if (st) STG_HB(0, 1, ku2);
        BAR; LGKM0; PRI1; MFQ(1, 0); PRI0; BAR;
        // P6: quadrant (1,1); stage A-LO(buf1, u+3)
        LDBF(1, 1);
        if (st) STG_HA(1, 0, ku3);
        BAR; LGKM0; PRI1; MFQ(1, 1); PRI0; BAR;
        // P7: quadrant (0,1); stage A-HI+B-LO(buf1, u+3); counted wait for buf0
        if (st) { STG_HA(1, 1, ku3); STG_HB(1, 0, ku3); VMW(6); } else { VMW(0); }
        BAR; PRI1; MFQ(0, 1); PRI0; BAR;
    }
}

// ---------------------------------------------------------------------------
// 128x128 4-wave core (m97 structure) — kept for the small window GEMMs.
// ---------------------------------------------------------------------------
__device__ __forceinline__ void mfma_core(
    const unsigned short* __restrict__ A, int lda,
    const unsigned short* __restrict__ Bt, int ldb, int K,
    unsigned short* As, unsigned short* Bs, f32x4 (&acc)[4][4])
{
    const int tid = threadIdx.x;
    const int wv = tid >> 6, lane = tid & 63;
    const int wr = wv >> 1, wc = wv & 1;

#pragma unroll
    for (int m = 0; m < 4; ++m)
#pragma unroll
        for (int n = 0; n < 4; ++n) acc[m][n] = (f32x4){0.f, 0.f, 0.f, 0.f};

    for (int k0 = 0; k0 < K; k0 += 64) {
#pragma unroll
        for (int it = 0; it < 4; ++it) {
            int rbase = wv * 32 + it * 8;
            const unsigned short* g =
                A + (size_t)(rbase + (lane >> 3)) * lda + k0 + (lane & 7) * 8;
            gld_lds16(g, As + rbase * 64);
        }
#pragma unroll
        for (int it = 0; it < 4; ++it) {
            int rbase = wv * 32 + it * 8;
            const unsigned short* g =
                Bt + (size_t)(rbase + (lane >> 3)) * ldb + k0 + (lane & 7) * 8;
            gld_lds16(g, Bs + rbase * 64);
        }
        __syncthreads();

#pragma unroll
        for (int ks = 0; ks < 2; ++ks) {
            bf16x8 af[4], bfr[4];
            const int kof = ks * 32 + (lane >> 4) * 8;
#pragma unroll
            for (int m = 0; m < 4; ++m)
                af[m] = *(const bf16x8*)(As + (wr * 64 + m * 16 + (lane & 15)) * 64 + kof);
#pragma unroll
            for (int n = 0; n < 4; ++n)
                bfr[n] = *(const bf16x8*)(Bs + (wc * 64 + n * 16 + (lane & 15)) * 64 + kof);
#pragma unroll
            for (int m = 0; m < 4; ++m)
#pragma unroll
                for (int n = 0; n < 4; ++n)
                    acc[m][n] = __builtin_amdgcn_mfma_f32_16x16x32_bf16(
                        af[m], bfr[n], acc[m][n], 0, 0, 0);
        }
        __syncthreads();
    }
}

// ---------------------------------------------------------------------------
// Prepass kernels
// ---------------------------------------------------------------------------
__global__ __launch_bounds__(256) void k_prep_x(const float* __restrict__ x,
                                                unsigned short* __restrict__ xb)
{
    int i = blockIdx.x * 256 + threadIdx.x;
    float4 a = *(const float4*)&x[(size_t)i * 8];
    float4 b = *(const float4*)&x[(size_t)i * 8 + 4];
    ushort4 lo, hi;
    lo.x = f2b(a.x); lo.y = f2b(a.y); lo.z = f2b(a.z); lo.w = f2b(a.w);
    hi.x = f2b(b.x); hi.y = f2b(b.y); hi.z = f2b(b.z); hi.w = f2b(b.w);
    *(ushort4*)&xb[(size_t)i * 8] = lo;
    *(ushort4*)&xb[(size_t)i * 8 + 4] = hi;
}

__global__ __launch_bounds__(256) void k_transpose(const float* __restrict__ src,
    int src_ld, int col0, int R, unsigned short* __restrict__ dst)
{
    __shared__ float T[32][33];
    const int r0 = blockIdx.y * 32, c0 = blockIdx.x * 32;
    const int cx = threadIdx.x & 31, ry = threadIdx.x >> 5;
#pragma unroll
    for (int i = 0; i < 4; ++i)
        T[ry + 8 * i][cx] = src[(size_t)(r0 + ry + 8 * i) * src_ld + col0 + c0 + cx];
    __syncthreads();
#pragma unroll
    for (int i = 0; i < 4; ++i)
        dst[(size_t)(c0 + ry + 8 * i) * R + r0 + cx] = f2b(T[cx][ry + 8 * i]);
}

__global__ __launch_bounds__(256) void k_zero_kpad(unsigned short* __restrict__ kbuf)
{
    int t = blockIdx.x * 256 + threadIdx.x;
    int b = t >> 14, r = t & 16383;
    float4 z = {0.f, 0.f, 0.f, 0.f};
    *(float4*)&kbuf[(size_t)b * KPAD * DIM + (size_t)r * 8] = z;
}

__global__ __launch_bounds__(256) void k_zero_ktpad(unsigned short* __restrict__ ktr)
{
    int t = blockIdx.x * 256 + threadIdx.x;
    int b = t >> 14, rem = t & 16383;
    int d = rem >> 4, s = rem & 15;
    float4 z = {0.f, 0.f, 0.f, 0.f};
    *(float4*)&ktr[((size_t)b * DIM + d) * KPAD + s * 8] = z;
}

// ---------------------------------------------------------------------------
// qk-proj (256^2 8-phase): xb(16384x1024) x wqkvT(2048x1024)^T.
// grid 512 blocks x 512 thr; XCD swizzle chunk=64 (512%8==0).
// ---------------------------------------------------------------------------
__global__ __launch_bounds__(512, 2) void k_gemm_qk(
    const unsigned short* __restrict__ xb, const unsigned short* __restrict__ wqkvT,
    unsigned short* __restrict__ qbuf, unsigned short* __restrict__ kbuf,
    unsigned short* __restrict__ ktr)
{
    __shared__ unsigned short lds[65536];   // 128 KB
    const int tid = threadIdx.x, wid = tid >> 6, lane = tid & 63;
    const int wr = wid >> 2, wc = wid & 3;
    const int wg = blockIdx.x;
    const int x = (wg & 7) * 64 + (wg >> 3);
    const int bm = (x & 63) * 256;
    const int bn = (x >> 6) * 256;          // consecutive-in-XCD share B panel

    f32x4 acc[8][4];
    core256(xb + (size_t)bm * DIM, DIM, wqkvT + (size_t)bn * DIM, DIM, DIM,
            lds, acc, wid, lane, wr, wc);

    const int fr = lane & 15;
#pragma unroll
    for (int m = 0; m < 8; ++m) {
        const int row0 = bm + wr * 128 + m * 16 + (lane >> 4) * 4;
#pragma unroll
        for (int n = 0; n < 4; ++n) {
            const int col = bn + wc * 64 + n * 16 + fr;
            if (col < DIM) {
#pragma unroll
                for (int r = 0; r < 4; ++r)
                    qbuf[(size_t)(row0 + r) * DIM + col] = f2b(acc[m][n][r]);
            } else {
                const int d = col - DIM;
                const int b = row0 >> 12, tok0 = row0 & 4095;
#pragma unroll
                for (int r = 0; r < 4; ++r)
                    kbuf[((size_t)b * KPAD + 128 + tok0 + r) * DIM + d] = f2b(acc[m][n][r]);
                ushort4 kt;
                kt.x = f2b(acc[m][n][0]); kt.y = f2b(acc[m][n][1]);
                kt.z = f2b(acc[m][n][2]); kt.w = f2b(acc[m][n][3]);
                *(ushort4*)&ktr[((size_t)b * DIM + d) * KPAD + 128 + tok0] = kt;
            }
        }
    }
}

// ---------------------------------------------------------------------------
// out-proj (256^2 8-phase): aout(16384x1024) x woutT(1024x1024)^T + bias.
// grid 256 blocks; XCD swizzle chunk=32.
// ---------------------------------------------------------------------------
__global__ __launch_bounds__(512, 2) void k_out(
    const unsigned short* __restrict__ aout, const unsigned short* __restrict__ woutT,
    const float* __restrict__ bias, float* __restrict__ out)
{
    __shared__ unsigned short lds[65536];
    const int tid = threadIdx.x, wid = tid >> 6, lane = tid & 63;
    const int wr = wid >> 2, wc = wid & 3;
    const int wg = blockIdx.x;
    const int x = (wg & 7) * 32 + (wg >> 3);
    const int bm = (x & 63) * 256;
    const int bn = (x >> 6) * 256;

    f32x4 acc[8][4];
    core256(aout + (size_t)bm * DIM, DIM, woutT + (size_t)bn * DIM, DIM, DIM,
            lds, acc, wid, lane, wr, wc);

    const int fr = lane & 15;
#pragma unroll
    for (int m = 0; m < 8; ++m) {
        const int row0 = bm + wr * 128 + m * 16 + (lane >> 4) * 4;
#pragma unroll
        for (int n = 0; n < 4; ++n) {
            const int col = bn + wc * 64 + n * 16 + fr;
            const float bb = bias[col];
#pragma unroll
            for (int r = 0; r < 4; ++r)
                out[(size_t)(row0 + r) * DIM + col] = acc[m][n][r] + bb;
        }
    }
}

// ---------------------------------------------------------------------------
// sim = q.k2^T * scale, masked -> fp32. grid (2, 128). (unchanged)
// ---------------------------------------------------------------------------
__global__ __launch_bounds__(256) void k_sim(
    const unsigned short* __restrict__ qbuf, const unsigned short* __restrict__ kbuf,
    float* __restrict__ sim)
{
    __shared__ unsigned short As[128 * 64], Bs[128 * 64];
    f32x4 acc[4][4];
    const int win = blockIdx.y, ct = blockIdx.x;
    const int b = win >> 5, w = win & 31;
    const unsigned short* Ap = qbuf + ((size_t)b * SEQ + w * WIN) * DIM;
    const unsigned short* Bp = kbuf + ((size_t)b * KPAD + w * WIN + ct * 128) * DIM;
    mfma_core(Ap, DIM, Bp, DIM, DIM, As, Bs, acc);

    const int tid = threadIdx.x, wv = tid >> 6, lane = tid & 63;
    const int wr = wv >> 1, wc = wv & 1;
    const float scale = 0.03125f;
#pragma unroll
    for (int m = 0; m < 4; ++m) {
        const int qi0 = wr * 64 + m * 16 + (lane >> 4) * 4;
#pragma unroll
        for (int n = 0; n < 4; ++n) {
            const int jc = ct * 128 + wc * 64 + n * 16 + (lane & 15);
#pragma unroll
            for (int r = 0; r < 4; ++r) {
                const int qi = qi0 + r;
                float v = (jc > qi + WIN) ? -FLT_MAX : acc[m][n][r] * scale;
                sim[((size_t)win * WIN + qi) * TW + jc] = v;
            }
        }
    }
}

__global__ __launch_bounds__(256) void k_softmax(const float* __restrict__ sim,
                                                 unsigned short* __restrict__ attnb)
{
    const int row = blockIdx.x * 4 + (threadIdx.x >> 6);
    const int lane = threadIdx.x & 63;
    const float* p = sim + (size_t)row * TW;
    float4 v = *(const float4*)&p[lane * 4];
    float m = fmaxf(fmaxf(v.x, v.y), fmaxf(v.z, v.w));
#pragma unroll
    for (int off = 32; off; off >>= 1) m = fmaxf(m, __shfl_xor(m, off));
    float e0 = expf(v.x - m), e1 = expf(v.y - m);
    float e2 = expf(v.z - m), e3 = expf(v.w - m);
    float s = e0 + e1 + e2 + e3;
#pragma unroll
    for (int off = 32; off; off >>= 1) s += __shfl_xor(s, off);
    float inv = 1.f / s;
    ushort4 o;
    o.x = f2b(e0 * inv); o.y = f2b(e1 * inv); o.z = f2b(e2 * inv); o.w = f2b(e3 * inv);
    *(ushort4*)&attnb[(size_t)row * TW + lane * 4] = o;
}

__global__ __launch_bounds__(256) void k_pv(
    const unsigned short* __restrict__ attnb, const unsigned short* __restrict__ ktr,
    unsigned short* __restrict__ aout)
{
    __shared__ unsigned short As[128 * 64], Bs[128 * 64];
    f32x4 acc[4][4];
    const int win = blockIdx.y, ct = blockIdx.x;
    const int b = win >> 5, w = win & 31;
    const unsigned short* Ap = attnb + (size_t)win * WIN * TW;
    const unsigned short* Bp = ktr + ((size_t)b * DIM + ct * 128) * KPAD + w * WIN;
    mfma_core(Ap, TW, Bp, KPAD, TW, As, Bs, acc);

    const int tid = threadIdx.x, wv = tid >> 6, lane = tid & 63;
    const int wr = wv >> 1, wc = wv & 1;
#pragma unroll
    for (int m = 0; m < 4; ++m) {
        const int row0 = wr * 64 + m * 16 + (lane >> 4) * 4;
#pragma unroll
        for (int n = 0; n < 4; ++n) {
            const int col = ct * 128 + wc * 64 + n * 16 + (lane & 15);
#pragma unroll
            for (int r = 0; r < 4; ++r)
                aout[((size_t)b * SEQ + w * WIN + row0 + r) * DIM + col] =
                    f2b(acc[m][n][r]);
        }
    }
}

// ---------------------------------------------------------------------------
extern "C" void kernel_launch(void* const* d_in, const int* in_sizes, int n_in,
                              void* d_out, int out_size, void* d_ws, size_t ws_size,
                              hipStream_t stream)
{
    const float* x     = (const float*)d_in[0];
    const float* w_qkv = (const float*)d_in[1];
    const float* w_out = (const float*)d_in[2];
    const float* b_out = (const float*)d_in[3];
    float* out = (float*)d_out;

    char* p = (char*)d_ws;
    unsigned short* xb    = (unsigned short*)p; p += (size_t)NROWS * DIM * 2;
    unsigned short* wqkvT = (unsigned short*)p; p += (size_t)2 * DIM * DIM * 2;
    unsigned short* woutT = (unsigned short*)p; p += (size_t)DIM * DIM * 2;
    unsigned short* qbuf  = (unsigned short*)p; p += (size_t)NROWS * DIM * 2;
    unsigned short* kbuf  = (unsigned short*)p; p += (size_t)B_SZ * KPAD * DIM * 2;
    unsigned short* ktr   = (unsigned short*)p; p += (size_t)B_SZ * DIM * KPAD * 2;
    float*          simb  = (float*)p;          p += (size_t)NROWS * TW * 4;
    unsigned short* attnb = (unsigned short*)p; p += (size_t)NROWS * TW * 2;
    unsigned short* aout  = (unsigned short*)p; p += (size_t)NROWS * DIM * 2;

    k_prep_x<<<NROWS * DIM / 8 / 256, 256, 0, stream>>>(x, xb);
    k_transpose<<<dim3(2 * DIM / 32, DIM / 32), 256, 0, stream>>>(w_qkv, 3 * DIM, 0, DIM, wqkvT);
    k_transpose<<<dim3(DIM / 32, DIM / 32), 256, 0, stream>>>(w_out, DIM, 0, DIM, woutT);
    k_zero_kpad<<<256, 256, 0, stream>>>(kbuf);
    k_zero_ktpad<<<256, 256, 0, stream>>>(ktr);

    k_gemm_qk<<<512, 512, 0, stream>>>(xb, wqkvT, qbuf, kbuf, ktr);
    k_sim<<<dim3(2, B_SZ * NWIN), 256, 0, stream>>>(qbuf, kbuf, simb);
    k_softmax<<<NROWS / 4, 256, 0, stream>>>(simb, attnb);
    k_pv<<<dim3(DIM / 128, B_SZ * NWIN), 256, 0, stream>>>(attnb, ktr, aout);
    k_out<<<256, 512, 0, stream>>>(aout, woutT, b_out, out);
}